// Round 11
// baseline (17.247 us; speedup 1.0000x reference)
//
#include <hip/hip_runtime.h>

#define NCH      64
#define WW       97
#define NTHREADS 512

typedef float        f32x4 __attribute__((ext_vector_type(4)));
typedef _Float16     h16x4 __attribute__((ext_vector_type(4)));
typedef unsigned int u32;
typedef unsigned int u32x2 __attribute__((ext_vector_type(2)));

#define WEXP_STRIDE 33   // entries per channel (pad 32->33: rotate LDS bank pairs)
#define SIDT_STRIDE 68   // bytes per u-row (17 dwords: 2-way-free id reads)

// Fused kernel: batch-per-XCD swizzle + coalesced row staging through LDS.
// Output (c,t,u): own value x[b][c][64t+u]; weight-window id from bin of
// x[b][t][64u+c]. WG(b,t) stages row t's 4096 bin-ids in LDS (coalesced);
// swizzle keeps batch b's slab in one XCD L2 (2 batches resident = 4 MB).
__global__ __launch_bounds__(NTHREADS)
void pw_kernel(const float* __restrict__ x,
               const float* __restrict__ w,
               float* __restrict__ out) {
  __shared__ h16x4 wexp[NCH * WEXP_STRIDE];                  // 16.5 KB
  __shared__ __align__(8) unsigned char sidT[64 * SIDT_STRIDE]; // 4.25 KB

  const int g   = blockIdx.x;
  const int b   = (g & 7) | ((g >> 9) << 3);   // XCD = g%8 = b%8
  const int t   = (g >> 3) & 63;
  const int tid = threadIdx.x;

  // ---- decode output coords early so ALL global loads issue up front ----
  const int l  = tid & 63;
  const int wv = tid >> 6;               // 0..7
  const int q  = l & 15;                 // u-quad index
  const int a  = l >> 4;                 // 0..3
  const int u0 = q << 2;
  const int c0 = (wv << 3) + (a << 1);   // even channel pair start
  const size_t obase = (((size_t)(b * NCH + c0)) << 12) + ((size_t)(t << 6)) + u0;

  // row read (coalesced, 32 B/thread) + own reads — all in flight now
  const float* xrow = x + (((size_t)(b * NCH + t)) << 12);
  const f32x4 r0   = *reinterpret_cast<const f32x4*>(xrow + (tid << 3));
  const f32x4 r1   = *reinterpret_cast<const f32x4*>(xrow + (tid << 3) + 4);
  const f32x4 own0 = *reinterpret_cast<const f32x4*>(x + obase);
  const f32x4 own1 = *reinterpret_cast<const f32x4*>(x + obase + 4096);

  // ---- build monomial table from w (4 entries/thread; w is L2-hot) ----
  #pragma unroll
  for (int k = 0; k < 4; ++k) {
    const int r = tid + k * NTHREADS;   // [0, 2048)
    const int c = r >> 5, i = r & 31;
    const float* wr = w + c * WW + 3 * i;
    const float v0 = wr[0] * (-9.0f / 16.0f);
    const float v1 = wr[1] * (27.0f / 16.0f);
    const float v2 = wr[2] * (-27.0f / 16.0f);
    const float v3 = wr[3] * (9.0f / 16.0f);
    h16x4 h;
    h[3] = (_Float16)(v0 + v1 + v2 + v3);
    h[2] = (_Float16)(-v0 - v1 * (1.0f / 3.0f) + v2 * (1.0f / 3.0f) + v3);
    h[1] = (_Float16)(-v0 * (1.0f / 9.0f) - v1 - v2 - v3 * (1.0f / 9.0f));
    h[0] = (_Float16)( v0 * (1.0f / 9.0f) + v1 * (1.0f / 3.0f)
                     - v2 * (1.0f / 3.0f) - v3 * (1.0f / 9.0f));
    wexp[c * WEXP_STRIDE + i] = h;
  }

  // ---- pack 8 row ids -> one ds_write_b64 (thread owns row elems 8s..8s+7) ----
  {
    u32 p0 = 0, p1 = 0;
    #pragma unroll
    for (int i = 0; i < 4; ++i) {
      const float t0 = fmaf(r0[i], 16.0f, 16.0f);   // == (x+1)/2*32 bitwise
      int id0 = (int)t0;                             // trunc toward zero
      id0 = id0 < 0 ? 0 : (id0 > 31 ? 31 : id0);
      p0 |= (u32)id0 << (8 * i);
      const float t1 = fmaf(r1[i], 16.0f, 16.0f);
      int id1 = (int)t1;
      id1 = id1 < 0 ? 0 : (id1 > 31 ? 31 : id1);
      p1 |= (u32)id1 << (8 * i);
    }
    u32x2 pv; pv[0] = p0; pv[1] = p1;
    *reinterpret_cast<u32x2*>(&sidT[(tid >> 3) * SIDT_STRIDE + ((tid & 7) << 3)]) = pv;
  }
  __syncthreads();

  // ---- 4 id dwords: sidT[u0+i][c0&~3 .. +3] ----
  const int dwo = (c0 >> 2) << 2;
  u32 idw[4];
  #pragma unroll
  for (int i = 0; i < 4; ++i)
    idw[i] = *reinterpret_cast<const u32*>(&sidT[(u0 + i) * SIDT_STRIDE + dwo]);
  const int sh0 = (c0 & 3) * 8;

  #pragma unroll
  for (int j = 0; j < 2; ++j) {
    const f32x4 own = (j == 0) ? own0 : own1;
    const int cb = (c0 + j) * WEXP_STRIDE;
    const int sh = sh0 + 8 * j;
    f32x4 res;
    #pragma unroll
    for (int i = 0; i < 4; ++i) {
      // own bin id -> local coordinate (ids bitwise-identical to reference)
      const float xv = own[i];
      const float tt = fmaf(xv, 16.0f, 16.0f);
      int idm = (int)tt;
      idm = idm < 0 ? 0 : (idm > 31 ? 31 : idm);
      const float xin = fmaf(xv, 32.0f, fmaf((float)idm, -2.0f, 31.0f));

      // transposed id -> coefficient window (ds_read_b64, bank-rotated table)
      const int widx = (idw[i] >> sh) & 31;
      const h16x4 hc = wexp[cb + widx];
      res[i] = fmaf(fmaf(fmaf((float)hc[3], xin, (float)hc[2]), xin,
                         (float)hc[1]), xin, (float)hc[0]);
    }
    __builtin_nontemporal_store(res,
        reinterpret_cast<f32x4*>(out + obase + ((size_t)j << 12)));
  }
}

extern "C" void kernel_launch(void* const* d_in, const int* in_sizes, int n_in,
                              void* d_out, int out_size, void* d_ws, size_t ws_size,
                              hipStream_t stream) {
  const float* x = (const float*)d_in[0];
  const float* w = (const float*)d_in[1];
  float* out    = (float*)d_out;
  pw_kernel<<<dim3(2048), NTHREADS, 0, stream>>>(x, w, out);
}

// Round 12
// 16.301 us; speedup vs baseline: 1.0580x; 1.0580x over previous
//
#include <hip/hip_runtime.h>

#define NCH      64
#define WW       97
#define NTHREADS 512

typedef float        f32x4  __attribute__((ext_vector_type(4)));
typedef float        f32x4u __attribute__((ext_vector_type(4), aligned(4)));
typedef _Float16     h16x4  __attribute__((ext_vector_type(4)));
typedef _Float16     h16x8  __attribute__((ext_vector_type(8)));
typedef unsigned int u32;
typedef unsigned int u32x2 __attribute__((ext_vector_type(2)));

// Fused kernel: batch-per-XCD swizzle + coalesced row staging through LDS.
// Output (c,t,u): own value x[b][c][64t+u]; weight-window id from bin of
// x[b][t][64u+c]. WG(b,t) stages row t's 4096 bin-ids in LDS (coalesced);
// swizzle keeps batch b's slab in one XCD L2 (2 batches resident = 4 MB).
__global__ __launch_bounds__(NTHREADS)
void pw_kernel(const float* __restrict__ x,
               const float* __restrict__ w,
               float* __restrict__ out) {
  __shared__ h16x4 wexp[NCH * 32];                       // 16 KB monomial f16 coeffs
  __shared__ __align__(8) unsigned char sidT[64 * 72];   // ids[u][c], row stride 72

  const int g   = blockIdx.x;
  const int b   = (g & 7) | ((g >> 9) << 3);   // XCD = g%8 = b%8
  const int t   = (g >> 3) & 63;
  const int tid = threadIdx.x;

  // ---- row read (issued first; fully coalesced: 32 B/thread) ----
  const float* xrow = x + (((size_t)(b * NCH + t)) << 12);
  const f32x4 r0 = *reinterpret_cast<const f32x4*>(xrow + (tid << 3));
  const f32x4 r1 = *reinterpret_cast<const f32x4*>(xrow + (tid << 3) + 4);

  // ---- build monomial table: 2 entry-PAIRS/thread, vector loads ----
  // P(x) = a3 x^3 + a2 x^2 + a1 x + a0 over nodes {-1,-1/3,1/3,1}:
  // A=w3-w0, B=w3+w0, C=w1-w2, D=w1+w2 ->
  //   a3 = 9/16 A + 27/16 C;  a2 = 9/16 (B-D)
  //   a1 = -A/16 - 27/16 C;   a0 = -B/16 + 9/16 D
  #pragma unroll
  for (int k = 0; k < 2; ++k) {
    const int pr = tid + k * NTHREADS;     // pair index [0, 1024)
    const int c  = pr >> 4, k2 = pr & 15;  // entries 2k2, 2k2+1 of channel c
    const float* wr = w + c * WW + 6 * k2;
    const f32x4u wa = *reinterpret_cast<const f32x4u*>(wr);      // w[6k2..+3]
    const f32x4u wb = *reinterpret_cast<const f32x4u*>(wr + 3);  // w[6k2+3..+6]
    h16x8 hh;
    {
      const float A = wa[3] - wa[0], B = wa[3] + wa[0];
      const float C = wa[1] - wa[2], D = wa[1] + wa[2];
      hh[0] = (_Float16)fmaf(D, 0.5625f, B * -0.0625f);
      hh[1] = (_Float16)fmaf(C, -1.6875f, A * -0.0625f);
      hh[2] = (_Float16)((B - D) * 0.5625f);
      hh[3] = (_Float16)fmaf(C, 1.6875f, A * 0.5625f);
    }
    {
      const float A = wb[3] - wb[0], B = wb[3] + wb[0];
      const float C = wb[1] - wb[2], D = wb[1] + wb[2];
      hh[4] = (_Float16)fmaf(D, 0.5625f, B * -0.0625f);
      hh[5] = (_Float16)fmaf(C, -1.6875f, A * -0.0625f);
      hh[6] = (_Float16)((B - D) * 0.5625f);
      hh[7] = (_Float16)fmaf(C, 1.6875f, A * 0.5625f);
    }
    *reinterpret_cast<h16x8*>(&wexp[(c << 5) + (k2 << 1)]) = hh;  // ds_write_b128
  }

  // ---- pack 8 row ids -> one ds_write_b64 (thread owns row elems 8s..8s+7) ----
  {
    u32 p0 = 0, p1 = 0;
    #pragma unroll
    for (int i = 0; i < 4; ++i) {
      const float t0 = fmaf(r0[i], 16.0f, 16.0f);   // == (x+1)/2*32 bitwise
      int id0 = (int)t0;                             // trunc toward zero
      id0 = id0 < 0 ? 0 : (id0 > 31 ? 31 : id0);
      p0 |= (u32)id0 << (8 * i);
      const float t1 = fmaf(r1[i], 16.0f, 16.0f);
      int id1 = (int)t1;
      id1 = id1 < 0 ? 0 : (id1 > 31 ? 31 : id1);
      p1 |= (u32)id1 << (8 * i);
    }
    u32x2 pv; pv[0] = p0; pv[1] = p1;
    *reinterpret_cast<u32x2*>(&sidT[(tid >> 3) * 72 + ((tid & 7) << 3)]) = pv;
  }
  __syncthreads();

  // ---- main body: thread owns c-pair x u-quad (8 outputs) ----
  const int l  = tid & 63;
  const int wv = tid >> 6;            // 0..7
  const int q  = l & 15;              // u-quad index
  const int a  = l >> 4;              // 0..3
  const int u0 = q << 2;
  const int c0 = (wv << 3) + (a << 1);   // even channel pair start

  // 4 id dwords: sidT[u0+i][c0&~3 .. +3]
  const int dwo = (c0 >> 2) << 2;
  u32 idw[4];
  #pragma unroll
  for (int i = 0; i < 4; ++i)
    idw[i] = *reinterpret_cast<const u32*>(&sidT[(u0 + i) * 72 + dwo]);
  const int sh0 = (c0 & 3) * 8;

  const size_t obase = (((size_t)(b * NCH + c0)) << 12) + ((size_t)(t << 6)) + u0;

  #pragma unroll
  for (int j = 0; j < 2; ++j) {
    const f32x4 own = *reinterpret_cast<const f32x4*>(x + obase + ((size_t)j << 12));
    const int cb = (c0 + j) << 5;
    const int sh = sh0 + 8 * j;
    f32x4 res;
    #pragma unroll
    for (int i = 0; i < 4; ++i) {
      // own bin id -> local coordinate (ids bitwise-identical to reference)
      const float xv = own[i];
      const float tt = fmaf(xv, 16.0f, 16.0f);
      int idm = (int)tt;
      idm = idm < 0 ? 0 : (idm > 31 ? 31 : idm);
      const float xin = fmaf(xv, 32.0f, fmaf((float)idm, -2.0f, 31.0f));

      // transposed id -> coefficient window (ds_read_b64)
      const int widx = (idw[i] >> sh) & 31;
      const h16x4 hc = wexp[cb + widx];
      res[i] = fmaf(fmaf(fmaf((float)hc[3], xin, (float)hc[2]), xin,
                         (float)hc[1]), xin, (float)hc[0]);
    }
    __builtin_nontemporal_store(res,
        reinterpret_cast<f32x4*>(out + obase + ((size_t)j << 12)));
  }
}

extern "C" void kernel_launch(void* const* d_in, const int* in_sizes, int n_in,
                              void* d_out, int out_size, void* d_ws, size_t ws_size,
                              hipStream_t stream) {
  const float* x = (const float*)d_in[0];
  const float* w = (const float*)d_in[1];
  float* out    = (float*)d_out;
  pw_kernel<<<dim3(2048), NTHREADS, 0, stream>>>(x, w, out);
}